// Round 8
// baseline (90.979 us; speedup 1.0000x reference)
//
#include <hip/hip_runtime.h>
#include <math.h>

#define BIG_NEG (-1.0e9f)

constexpr int B = 16, T = 2048, D = 64, C = 32, NF = 16;

typedef float f32x4 __attribute__((ext_vector_type(4)));

// ws layout (floats):
//   [0..63]                 inv_var
//   [64]                    log_norm
//   [96..127]               cc[c] = -0.5*mm[c] + log_norm
//   [128 .. 128+K*C)        length_lp (room up to K=32)
//   [1152 .. 1152+C*D)      wm[c][d] = means[c][d]*inv_var[d]
//   [4096 .. 4096+B*C*T)    emission, TRANSPOSED layout (b,c,t)
//   [.. + B*(T+1)*C)        cs, layout (b,t,c)

// ---------------------------------------------------------------------------
// prep: iv, log_norm, wm, cc, length_lp, trans_lp, init_lp — one block
// ---------------------------------------------------------------------------
__global__ __launch_bounds__(1024) void prep_kernel(
    const float* __restrict__ P,       // (D,NF)
    const float* __restrict__ TL,      // (C,D)
    const float* __restrict__ TR,      // (C,D)
    const float* __restrict__ STD,     // (D,)
    const float* __restrict__ MEANS,   // (C,D)
    const float* __restrict__ PLR,     // (C,)
    const float* __restrict__ LOGITS,  // (C,)
    float* __restrict__ ws,
    float* __restrict__ out_trans,     // (C,C)
    float* __restrict__ out_init,      // (C,)
    int K)
{
    __shared__ float left[C][NF];
    __shared__ float right[C][NF];
    __shared__ float M[C][C + 1];
    __shared__ float lse[C];
    __shared__ float ilse;
    __shared__ float siv[D];
    __shared__ float red[D];
    __shared__ float slogn;

    const int tid = threadIdx.x;

    // ---- phase 0: independent loads/transforms ----
    if (tid < D) {
        float s = STD[tid];
        float v = 1.0f / (s * s);
        siv[tid] = v;
        ws[tid] = v;
        red[tid] = logf(s);
    }
    if (tid < C * NF) {
        int c = tid >> 4, f = tid & (NF - 1);
        float aL = 0.0f, aR = 0.0f;
        for (int d = 0; d < D; ++d) {
            float p = P[d * NF + f];
            aL = fmaf(TL[c * D + d], p, aL);
            aR = fmaf(TR[c * D + d], p, aR);
        }
        left[c][f] = aL;
        right[c][f] = aR;
    }
    for (int i = tid; i < K * C; i += 1024) {
        int k = i >> 5, c = i & 31;
        float plr = PLR[c];
        float kk = (float)(k + 1);
        ws[128 + i] = kk * plr - expf(plr) - lgammaf(kk + 1.0f);
    }
    __syncthreads();

    // ---- phase 1 ----
    if (tid == 0) {
        float acc = 0.0f;
        for (int d = 0; d < D; ++d) acc += red[d];
        float ln = -acc - 58.81206612510332f;  // 0.5*64*log(2*pi)
        slogn = ln;
        ws[64] = ln;
    }
    for (int i = tid; i < C * D; i += 1024)
        ws[1152 + i] = MEANS[i] * siv[i & 63];

    {
        int i = tid >> 5, j = tid & 31;
        float acc = 0.0f;
        for (int f = 0; f < NF; ++f) acc = fmaf(right[i][f], left[j][f], acc);
        M[i][j] = acc;
    }
    __syncthreads();

    // ---- phase 2 ----
    if (tid >= 64 && tid < 64 + C) {
        int c = tid - 64;
        float mm = 0.0f;
        for (int d = 0; d < D; ++d) {
            float m = MEANS[c * D + d];
            mm = fmaf(m * m, siv[d], mm);
        }
        ws[96 + c] = -0.5f * mm + slogn;
    }
    if (tid < C) {
        int j = tid;
        float mx = -INFINITY;
        for (int i = 0; i < C; ++i) mx = fmaxf(mx, M[i][j]);
        float s = 0.0f;
        for (int i = 0; i < C; ++i) s += expf(M[i][j] - mx);
        lse[j] = logf(s) + mx;
    }
    if (tid == 32) {
        float mx = -INFINITY;
        for (int i = 0; i < C; ++i) mx = fmaxf(mx, LOGITS[i]);
        float s = 0.0f;
        for (int i = 0; i < C; ++i) s += expf(LOGITS[i] - mx);
        ilse = logf(s) + mx;
    }
    __syncthreads();

    {
        int i = tid >> 5, j = tid & 31;
        out_trans[i * C + j] = M[i][j] - lse[j];
    }
    if (tid < C) out_init[tid] = LOGITS[tid] - ilse;
}

// ---------------------------------------------------------------------------
// emission: em_T[b,c,t] = xm - 0.5*xx + cc[c]
// grid remapped for b->XCD affinity: blockIdx = tc*16 + b  (XCD = b%8)
// ---------------------------------------------------------------------------
__global__ __launch_bounds__(256) void emission_kernel(
    const float* __restrict__ feat,    // (B*T, D)
    const float* __restrict__ ws,
    float* __restrict__ emT)           // (B, C, T)
{
    const float* __restrict__ iv = ws;
    const float* __restrict__ cc = ws + 96;
    const float* __restrict__ wm = ws + 1152;

    const int tid = threadIdx.x;
    const int b  = blockIdx.x & 15;
    const int tc = blockIdx.x >> 4;
    const int j = tid & 15;        // c-pair index
    const int i = tid >> 4;        // t-pair index within block
    const int tl = tc * 32 + 2 * i;
    const size_t tg = (size_t)b * T + tl;

    const float* f0p = feat + tg * D;
    const float* f1p = f0p + D;
    const float* w0p = wm + (2 * j) * D;
    const float* w1p = w0p + D;

    float a00 = 0.f, a01 = 0.f, a10 = 0.f, a11 = 0.f;
    float xx0 = 0.f, xx1 = 0.f;

#pragma unroll
    for (int q = 0; q < 16; ++q) {
        const float4 f0 = *(const float4*)(f0p + 4 * q);
        const float4 f1 = *(const float4*)(f1p + 4 * q);
        const float4 w0 = *(const float4*)(w0p + 4 * q);
        const float4 w1 = *(const float4*)(w1p + 4 * q);
        const float4 v4 = *(const float4*)(iv + 4 * q);

        a00 = fmaf(f0.x, w0.x, a00); a00 = fmaf(f0.y, w0.y, a00);
        a00 = fmaf(f0.z, w0.z, a00); a00 = fmaf(f0.w, w0.w, a00);
        a01 = fmaf(f0.x, w1.x, a01); a01 = fmaf(f0.y, w1.y, a01);
        a01 = fmaf(f0.z, w1.z, a01); a01 = fmaf(f0.w, w1.w, a01);
        a10 = fmaf(f1.x, w0.x, a10); a10 = fmaf(f1.y, w0.y, a10);
        a10 = fmaf(f1.z, w0.z, a10); a10 = fmaf(f1.w, w0.w, a10);
        a11 = fmaf(f1.x, w1.x, a11); a11 = fmaf(f1.y, w1.y, a11);
        a11 = fmaf(f1.z, w1.z, a11); a11 = fmaf(f1.w, w1.w, a11);

        xx0 = fmaf(f0.x * v4.x, f0.x, xx0); xx0 = fmaf(f0.y * v4.y, f0.y, xx0);
        xx0 = fmaf(f0.z * v4.z, f0.z, xx0); xx0 = fmaf(f0.w * v4.w, f0.w, xx0);
        xx1 = fmaf(f1.x * v4.x, f1.x, xx1); xx1 = fmaf(f1.y * v4.y, f1.y, xx1);
        xx1 = fmaf(f1.z * v4.z, f1.z, xx1); xx1 = fmaf(f1.w * v4.w, f1.w, xx1);
    }

    const float c0 = cc[2 * j], c1 = cc[2 * j + 1];
    float* p0 = emT + ((size_t)(b * C + 2 * j)) * T + tl;
    float* p1 = p0 + T;
    *(float2*)p0 = make_float2(a00 - 0.5f * xx0 + c0, a10 - 0.5f * xx1 + c0);
    *(float2*)p1 = make_float2(a01 - 0.5f * xx0 + c1, a11 - 0.5f * xx1 + c1);
}

// ---------------------------------------------------------------------------
// scan: cumsum over T per (b,c); grid remapped: blockIdx = c*16 + b (XCD=b%8)
// wave64 shuffle scan, single barrier.
// ---------------------------------------------------------------------------
__global__ __launch_bounds__(256) void scan_kernel(
    const float* __restrict__ emT,     // (B,C,T)
    float* __restrict__ cs)            // (B,T+1,C)
{
    __shared__ float wsum[4];
    const int tid = threadIdx.x;
    const int b = blockIdx.x & 15, c = blockIdx.x >> 4;
    const int lane = tid & 63, wid = tid >> 6;

    const float* ebase = emT + ((size_t)(b * C + c)) * T + tid * 8;
    const f32x4 v0 = *(const f32x4*)ebase;
    const f32x4 v1 = *(const f32x4*)(ebase + 4);

    float loc[8];
    float run = 0.0f;
    run += v0.x; loc[0] = run;
    run += v0.y; loc[1] = run;
    run += v0.z; loc[2] = run;
    run += v0.w; loc[3] = run;
    run += v1.x; loc[4] = run;
    run += v1.y; loc[5] = run;
    run += v1.z; loc[6] = run;
    run += v1.w; loc[7] = run;

    // wave64 inclusive scan of per-thread totals
    float sc = run;
#pragma unroll
    for (int off = 1; off < 64; off <<= 1) {
        float v = __shfl_up(sc, off, 64);
        if (lane >= off) sc += v;
    }
    if (lane == 63) wsum[wid] = sc;
    __syncthreads();
    float wpre = 0.0f;
#pragma unroll
    for (int w = 0; w < 3; ++w)
        wpre += (w < wid) ? wsum[w] : 0.0f;

    const float excl = wpre + sc - run;

    const int t0 = tid * 8;
    float* cbase = cs + ((size_t)b * (T + 1)) * C + c;
    if (tid == 0) cbase[0] = 0.0f;
#pragma unroll
    for (int j = 0; j < 8; ++j)
        cbase[(size_t)(t0 + j + 1) * C] = excl + loc[j];
}

// ---------------------------------------------------------------------------
// span v6: block = (b, t-chunk of 64). LDS-staged cs rows + llp; k-outer
// contiguous panel writes. (identical to round 7 — this round measures it)
// ---------------------------------------------------------------------------
template<int KT>
__global__ __launch_bounds__(256) void span_kernel_t(
    const float* __restrict__ cs,      // (B,T+1,C)
    const float* __restrict__ llp,     // (KT,C)
    float* __restrict__ out)           // (B,KT,T,C)
{
    constexpr int ROWS = 64 + KT + 1;  // rows t0-KT .. t0+64
    __shared__ float slds[ROWS * C];
    __shared__ float sllp[KT * C];

    const int tid = threadIdx.x;
    const int b = blockIdx.x & 15;
    const int t0 = (blockIdx.x >> 4) << 6;   // chunk * 64

    const float* csb = cs + (size_t)b * (T + 1) * C;
    for (int i = tid; i < ROWS * C; i += 256) {
        int r = t0 - KT + (i >> 5);
        slds[i] = csb[(size_t)(r < 0 ? 0 : r) * C + (i & 31)];
    }
    for (int i = tid; i < KT * C; i += 256) sllp[i] = llp[i];
    __syncthreads();

    const int c4 = (tid & 7) << 2;
    const int tb = tid >> 3;                 // 0..31
    const int ja = tb + KT;                  // LDS row of cs[t0+tb]
    const int jb = ja + 32;                  // LDS row of cs[t0+32+tb]
    const int ta = t0 + tb;
    const int tbig = t0 + 32 + tb;

    const f32x4 ea = *(const f32x4*)&slds[(ja + 1) * C + c4];
    const f32x4 eb = *(const f32x4*)&slds[(jb + 1) * C + c4];

    float* ob = out + ((size_t)(b * KT) * T + t0) * C + c4;

#pragma unroll
    for (int k = 0; k < KT; ++k) {
        const f32x4 lv = *(const f32x4*)&sllp[k * C + c4];
        const f32x4 sa = *(const f32x4*)&slds[(ja - k) * C + c4];
        const f32x4 sb = *(const f32x4*)&slds[(jb - k) * C + c4];
        f32x4 ra = ea - sa + lv;
        f32x4 rb = eb - sb + lv;
        if (ta < k) ra = BIG_NEG + lv;
        if (tbig < k) rb = BIG_NEG + lv;
        float* op = ob + (size_t)k * T * C;
        *(f32x4*)(op + tb * C) = ra;
        *(f32x4*)(op + (32 + tb) * C) = rb;
    }
}

// runtime-K fallback (dynamic LDS)
__global__ __launch_bounds__(256) void span_kernel_rt(
    const float* __restrict__ cs,
    const float* __restrict__ llp,
    float* __restrict__ out,
    int K)
{
    extern __shared__ float dyn[];
    float* slds = dyn;                 // (64+K+1) * C
    float* sllp = dyn + (64 + K + 1) * C;

    const int tid = threadIdx.x;
    const int b = blockIdx.x & 15;
    const int t0 = (blockIdx.x >> 4) << 6;
    const int ROWS = 64 + K + 1;

    const float* csb = cs + (size_t)b * (T + 1) * C;
    for (int i = tid; i < ROWS * C; i += 256) {
        int r = t0 - K + (i >> 5);
        slds[i] = csb[(size_t)(r < 0 ? 0 : r) * C + (i & 31)];
    }
    for (int i = tid; i < K * C; i += 256) sllp[i] = llp[i];
    __syncthreads();

    const int c4 = (tid & 7) << 2;
    const int tb = tid >> 3;
    const int ja = tb + K;
    const int jb = ja + 32;
    const int ta = t0 + tb;
    const int tbig = t0 + 32 + tb;

    const f32x4 ea = *(const f32x4*)&slds[(ja + 1) * C + c4];
    const f32x4 eb = *(const f32x4*)&slds[(jb + 1) * C + c4];

    float* ob = out + ((size_t)(b * K) * T + t0) * C + c4;

    for (int k = 0; k < K; ++k) {
        const f32x4 lv = *(const f32x4*)&sllp[k * C + c4];
        const f32x4 sa = *(const f32x4*)&slds[(ja - k) * C + c4];
        const f32x4 sb = *(const f32x4*)&slds[(jb - k) * C + c4];
        f32x4 ra = ea - sa + lv;
        f32x4 rb = eb - sb + lv;
        if (ta < k) ra = BIG_NEG + lv;
        if (tbig < k) rb = BIG_NEG + lv;
        float* op = ob + (size_t)k * T * C;
        *(f32x4*)(op + tb * C) = ra;
        *(f32x4*)(op + (32 + tb) * C) = rb;
    }
}

// ---------------------------------------------------------------------------
extern "C" void kernel_launch(void* const* d_in, const int* in_sizes, int n_in,
                              void* d_out, int out_size, void* d_ws, size_t ws_size,
                              hipStream_t stream) {
    const float* feat   = (const float*)d_in[0];
    const float* P      = (const float*)d_in[1];
    const float* TL     = (const float*)d_in[2];
    const float* TR     = (const float*)d_in[3];
    const float* MEANS  = (const float*)d_in[4];
    const float* STDV   = (const float*)d_in[5];
    const float* PLR    = (const float*)d_in[6];
    const float* LOGITS = (const float*)d_in[7];

    const int K = (out_size - (C * C + C)) / (B * T * C);

    float* ws  = (float*)d_ws;
    float* llp = ws + 128;
    float* emT = ws + 4096;
    float* cs  = emT + (size_t)B * T * C;

    float* out       = (float*)d_out;
    float* out_trans = out + (size_t)B * K * T * C;
    float* out_init  = out_trans + C * C;

    prep_kernel<<<1, 1024, 0, stream>>>(P, TL, TR, STDV, MEANS, PLR, LOGITS,
                                        ws, out_trans, out_init, K);
    emission_kernel<<<B * T / 32, 256, 0, stream>>>(feat, ws, emT);
    scan_kernel<<<B * C, 256, 0, stream>>>(emT, cs);

    // BISECTION ROUND: launch span 3x (identical, deterministic, last-write-
    // wins). Marginal span cost S = (dur_this_round - dur_round7) / 2.
    const int nblk = B * (T / 64);     // 512 blocks: (b, 32 chunks)
    if (K == 20) {
        span_kernel_t<20><<<nblk, 256, 0, stream>>>(cs, llp, out);
        span_kernel_t<20><<<nblk, 256, 0, stream>>>(cs, llp, out);
        span_kernel_t<20><<<nblk, 256, 0, stream>>>(cs, llp, out);
    } else if (K == 16) {
        span_kernel_t<16><<<nblk, 256, 0, stream>>>(cs, llp, out);
        span_kernel_t<16><<<nblk, 256, 0, stream>>>(cs, llp, out);
        span_kernel_t<16><<<nblk, 256, 0, stream>>>(cs, llp, out);
    } else if (K == 24) {
        span_kernel_t<24><<<nblk, 256, 0, stream>>>(cs, llp, out);
        span_kernel_t<24><<<nblk, 256, 0, stream>>>(cs, llp, out);
        span_kernel_t<24><<<nblk, 256, 0, stream>>>(cs, llp, out);
    } else {
        const size_t smem = (size_t)((64 + K + 1) + K) * C * sizeof(float);
        span_kernel_rt<<<nblk, 256, smem, stream>>>(cs, llp, out, K);
        span_kernel_rt<<<nblk, 256, smem, stream>>>(cs, llp, out, K);
        span_kernel_rt<<<nblk, 256, smem, stream>>>(cs, llp, out, K);
    }
}

// Round 9
// 55.654 us; speedup vs baseline: 1.6347x; 1.6347x over previous
//
#include <hip/hip_runtime.h>
#include <math.h>

#define BIG_NEG (-1.0e9f)

constexpr int B = 16, T = 2048, D = 64, C = 32, NF = 16;
constexpr int CS_STRIDE = 2052;   // T+1 padded to multiple of 4 (16B alignment)

typedef float f32x4 __attribute__((ext_vector_type(4)));

// ws layout (floats):
//   [0..63]                 inv_var
//   [64]                    log_norm
//   [96..127]               cc[c] = -0.5*mm[c] + log_norm
//   [128 .. 128+K*C)        length_lp (room up to K=32)
//   [1152 .. 1152+C*D)      wm[c][d] = means[c][d]*inv_var[d]
//   [4096 .. +B*C*T)        emission, layout (b,c,t)
//   [.. +B*C*CS_STRIDE)     cs, layout (b,c,t) padded rows
// total ~ 8.4 MB

// ---------------------------------------------------------------------------
// prep: iv, log_norm, wm, cc, length_lp, trans_lp, init_lp — one block
// ---------------------------------------------------------------------------
__global__ __launch_bounds__(1024) void prep_kernel(
    const float* __restrict__ P,       // (D,NF)
    const float* __restrict__ TL,      // (C,D)
    const float* __restrict__ TR,      // (C,D)
    const float* __restrict__ STD,     // (D,)
    const float* __restrict__ MEANS,   // (C,D)
    const float* __restrict__ PLR,     // (C,)
    const float* __restrict__ LOGITS,  // (C,)
    float* __restrict__ ws,
    float* __restrict__ out_trans,     // (C,C)
    float* __restrict__ out_init,      // (C,)
    int K)
{
    __shared__ float left[C][NF];
    __shared__ float right[C][NF];
    __shared__ float M[C][C + 1];
    __shared__ float lse[C];
    __shared__ float ilse;
    __shared__ float siv[D];
    __shared__ float slogn;

    const int tid = threadIdx.x;

    // ---- phase 0: independent loads/transforms ----
    if (tid < D) {
        float s = STD[tid];
        float v = 1.0f / (s * s);
        siv[tid] = v;
        ws[tid] = v;
        // wave 0 reduces sum(log(std)) via butterfly
        float lg = logf(s);
#pragma unroll
        for (int off = 32; off >= 1; off >>= 1)
            lg += __shfl_xor(lg, off, 64);
        if (tid == 0) {
            float ln = -lg - 58.81206612510332f;  // 0.5*64*log(2*pi)
            slogn = ln;
            ws[64] = ln;
        }
    }
    if (tid < C * NF) {
        int c = tid >> 4, f = tid & (NF - 1);
        float aL = 0.0f, aR = 0.0f;
        for (int d = 0; d < D; ++d) {
            float p = P[d * NF + f];
            aL = fmaf(TL[c * D + d], p, aL);
            aR = fmaf(TR[c * D + d], p, aR);
        }
        left[c][f] = aL;
        right[c][f] = aR;
    }
    for (int i = tid; i < K * C; i += 1024) {
        int k = i >> 5, c = i & 31;
        float plr = PLR[c];
        float kk = (float)(k + 1);
        ws[128 + i] = kk * plr - expf(plr) - lgammaf(kk + 1.0f);
    }
    __syncthreads();

    // ---- phase 1 ----
    for (int i = tid; i < C * D; i += 1024)
        ws[1152 + i] = MEANS[i] * siv[i & 63];

    {
        int i = tid >> 5, j = tid & 31;
        float acc = 0.0f;
        for (int f = 0; f < NF; ++f) acc = fmaf(right[i][f], left[j][f], acc);
        M[i][j] = acc;
    }
    __syncthreads();

    // ---- phase 2 ----
    if (tid >= 64 && tid < 64 + C) {
        int c = tid - 64;
        float mm = 0.0f;
        for (int d = 0; d < D; ++d) {
            float m = MEANS[c * D + d];
            mm = fmaf(m * m, siv[d], mm);
        }
        ws[96 + c] = -0.5f * mm + slogn;
    }
    if (tid < C) {
        int j = tid;
        float mx = -INFINITY;
        for (int i = 0; i < C; ++i) mx = fmaxf(mx, M[i][j]);
        float s = 0.0f;
        for (int i = 0; i < C; ++i) s += expf(M[i][j] - mx);
        lse[j] = logf(s) + mx;
    }
    if (tid == 32) {
        float mx = -INFINITY;
        for (int i = 0; i < C; ++i) mx = fmaxf(mx, LOGITS[i]);
        float s = 0.0f;
        for (int i = 0; i < C; ++i) s += expf(LOGITS[i] - mx);
        ilse = logf(s) + mx;
    }
    __syncthreads();

    {
        int i = tid >> 5, j = tid & 31;
        out_trans[i * C + j] = M[i][j] - lse[j];
    }
    if (tid < C) out_init[tid] = LOGITS[tid] - ilse;
}

// ---------------------------------------------------------------------------
// emission: em_T[b,c,t] = xm - 0.5*xx + cc[c]
// lane map: i = tid&15 (t-pair, fast) -> stores are 16-lane x 8B = 128B
// contiguous segments per c-row. blockIdx = tc*16 + b (XCD = b%8).
// ---------------------------------------------------------------------------
__global__ __launch_bounds__(256) void emission_kernel(
    const float* __restrict__ feat,    // (B*T, D)
    const float* __restrict__ ws,
    float* __restrict__ emT)           // (B, C, T)
{
    const float* __restrict__ iv = ws;
    const float* __restrict__ cc = ws + 96;
    const float* __restrict__ wm = ws + 1152;

    const int tid = threadIdx.x;
    const int b  = blockIdx.x & 15;
    const int tc = blockIdx.x >> 4;
    const int i = tid & 15;        // t-pair index (fast -> coalesced stores)
    const int j = tid >> 4;        // c-pair index
    const int tl = tc * 32 + 2 * i;
    const size_t tg = (size_t)b * T + tl;

    const float* f0p = feat + tg * D;
    const float* f1p = f0p + D;
    const float* w0p = wm + (2 * j) * D;
    const float* w1p = w0p + D;

    float a00 = 0.f, a01 = 0.f, a10 = 0.f, a11 = 0.f;
    float xx0 = 0.f, xx1 = 0.f;

#pragma unroll
    for (int q = 0; q < 16; ++q) {
        const float4 f0 = *(const float4*)(f0p + 4 * q);
        const float4 f1 = *(const float4*)(f1p + 4 * q);
        const float4 w0 = *(const float4*)(w0p + 4 * q);
        const float4 w1 = *(const float4*)(w1p + 4 * q);
        const float4 v4 = *(const float4*)(iv + 4 * q);

        a00 = fmaf(f0.x, w0.x, a00); a00 = fmaf(f0.y, w0.y, a00);
        a00 = fmaf(f0.z, w0.z, a00); a00 = fmaf(f0.w, w0.w, a00);
        a01 = fmaf(f0.x, w1.x, a01); a01 = fmaf(f0.y, w1.y, a01);
        a01 = fmaf(f0.z, w1.z, a01); a01 = fmaf(f0.w, w1.w, a01);
        a10 = fmaf(f1.x, w0.x, a10); a10 = fmaf(f1.y, w0.y, a10);
        a10 = fmaf(f1.z, w0.z, a10); a10 = fmaf(f1.w, w0.w, a10);
        a11 = fmaf(f1.x, w1.x, a11); a11 = fmaf(f1.y, w1.y, a11);
        a11 = fmaf(f1.z, w1.z, a11); a11 = fmaf(f1.w, w1.w, a11);

        xx0 = fmaf(f0.x * v4.x, f0.x, xx0); xx0 = fmaf(f0.y * v4.y, f0.y, xx0);
        xx0 = fmaf(f0.z * v4.z, f0.z, xx0); xx0 = fmaf(f0.w * v4.w, f0.w, xx0);
        xx1 = fmaf(f1.x * v4.x, f1.x, xx1); xx1 = fmaf(f1.y * v4.y, f1.y, xx1);
        xx1 = fmaf(f1.z * v4.z, f1.z, xx1); xx1 = fmaf(f1.w * v4.w, f1.w, xx1);
    }

    const float c0 = cc[2 * j], c1 = cc[2 * j + 1];
    float* p0 = emT + ((size_t)(b * C + 2 * j)) * T + tl;
    float* p1 = p0 + T;
    *(float2*)p0 = make_float2(a00 - 0.5f * xx0 + c0, a10 - 0.5f * xx1 + c0);
    *(float2*)p1 = make_float2(a01 - 0.5f * xx0 + c1, a11 - 0.5f * xx1 + c1);
}

// ---------------------------------------------------------------------------
// scan: cumsum over T per (b,c); blockIdx = c*16 + b (XCD = b%8).
// Writes cs in (b,c,t) padded layout: per-thread CONTIGUOUS aligned f32x4
// (exclusive-prefix trick), no cross-block line sharing.
// ---------------------------------------------------------------------------
__global__ __launch_bounds__(256) void scan_kernel(
    const float* __restrict__ emT,     // (B,C,T)
    float* __restrict__ cs)            // (B,C,CS_STRIDE)
{
    __shared__ float wsum[4];
    const int tid = threadIdx.x;
    const int b = blockIdx.x & 15, c = blockIdx.x >> 4;
    const int lane = tid & 63, wid = tid >> 6;

    const float* ebase = emT + ((size_t)(b * C + c)) * T + tid * 8;
    const f32x4 v0 = *(const f32x4*)ebase;
    const f32x4 v1 = *(const f32x4*)(ebase + 4);

    float loc[8];
    float run = 0.0f;
    run += v0.x; loc[0] = run;
    run += v0.y; loc[1] = run;
    run += v0.z; loc[2] = run;
    run += v0.w; loc[3] = run;
    run += v1.x; loc[4] = run;
    run += v1.y; loc[5] = run;
    run += v1.z; loc[6] = run;
    run += v1.w; loc[7] = run;

    // wave64 inclusive scan of per-thread totals
    float sc = run;
#pragma unroll
    for (int off = 1; off < 64; off <<= 1) {
        float v = __shfl_up(sc, off, 64);
        if (lane >= off) sc += v;
    }
    if (lane == 63) wsum[wid] = sc;
    __syncthreads();
    float wpre = 0.0f;
#pragma unroll
    for (int w = 0; w < 3; ++w)
        wpre += (w < wid) ? wsum[w] : 0.0f;

    const float excl = wpre + sc - run;   // exclusive prefix at t0 = tid*8

    // cs[t] = exclusive sum em[0..t-1]; thread writes t0..t0+7 contiguously
    float* cbase = cs + (size_t)(b * C + c) * CS_STRIDE;
    f32x4 o0 = {excl, excl + loc[0], excl + loc[1], excl + loc[2]};
    f32x4 o1 = {excl + loc[3], excl + loc[4], excl + loc[5], excl + loc[6]};
    *(f32x4*)(cbase + tid * 8) = o0;
    *(f32x4*)(cbase + tid * 8 + 4) = o1;
    if (tid == 255) cbase[T] = excl + loc[7];   // total
}

// ---------------------------------------------------------------------------
// span: block = (b, t-chunk of 64); stages cs rows [t0-KT, t0+64] from the
// (b,c,t) layout (c-major enumeration -> coalesced global reads), compute
// path identical to round 7. blockIdx = chunk*16 + b (XCD = b%8).
// ---------------------------------------------------------------------------
template<int KT>
__global__ __launch_bounds__(256) void span_kernel_t(
    const float* __restrict__ cs,      // (B,C,CS_STRIDE)
    const float* __restrict__ llp,     // (KT,C)
    float* __restrict__ out)           // (B,KT,T,C)
{
    constexpr int ROWS = 64 + KT + 1;  // rows t0-KT .. t0+64
    __shared__ float slds[ROWS * C];   // [row][c]
    __shared__ float sllp[KT * C];

    const int tid = threadIdx.x;
    const int b = blockIdx.x & 15;
    const int t0 = (blockIdx.x >> 4) << 6;   // chunk * 64

    const float* csb = cs + (size_t)b * C * CS_STRIDE;
    for (int i = tid; i < ROWS * C; i += 256) {
        const int c = i / ROWS;
        const int r = i - c * ROWS;
        int t = t0 - KT + r;
        if (t < 0) t = 0;
        slds[r * C + c] = csb[(size_t)c * CS_STRIDE + t];
    }
    for (int i = tid; i < KT * C; i += 256) sllp[i] = llp[i];
    __syncthreads();

    const int c4 = (tid & 7) << 2;
    const int tb = tid >> 3;                 // 0..31
    const int ja = tb + KT;                  // LDS row of cs[t0+tb]
    const int jb = ja + 32;                  // LDS row of cs[t0+32+tb]
    const int ta = t0 + tb;
    const int tbig = t0 + 32 + tb;

    const f32x4 ea = *(const f32x4*)&slds[(ja + 1) * C + c4];
    const f32x4 eb = *(const f32x4*)&slds[(jb + 1) * C + c4];

    float* ob = out + ((size_t)(b * KT) * T + t0) * C + c4;

#pragma unroll
    for (int k = 0; k < KT; ++k) {
        const f32x4 lv = *(const f32x4*)&sllp[k * C + c4];
        const f32x4 sa = *(const f32x4*)&slds[(ja - k) * C + c4];
        const f32x4 sb = *(const f32x4*)&slds[(jb - k) * C + c4];
        f32x4 ra = ea - sa + lv;
        f32x4 rb = eb - sb + lv;
        if (ta < k) ra = BIG_NEG + lv;
        if (tbig < k) rb = BIG_NEG + lv;
        float* op = ob + (size_t)k * T * C;
        *(f32x4*)(op + tb * C) = ra;
        *(f32x4*)(op + (32 + tb) * C) = rb;
    }
}

// runtime-K fallback (dynamic LDS)
__global__ __launch_bounds__(256) void span_kernel_rt(
    const float* __restrict__ cs,
    const float* __restrict__ llp,
    float* __restrict__ out,
    int K)
{
    extern __shared__ float dyn[];
    float* slds = dyn;                 // (64+K+1) * C
    float* sllp = dyn + (64 + K + 1) * C;

    const int tid = threadIdx.x;
    const int b = blockIdx.x & 15;
    const int t0 = (blockIdx.x >> 4) << 6;
    const int ROWS = 64 + K + 1;

    const float* csb = cs + (size_t)b * C * CS_STRIDE;
    for (int i = tid; i < ROWS * C; i += 256) {
        const int c = i / ROWS;
        const int r = i - c * ROWS;
        int t = t0 - K + r;
        if (t < 0) t = 0;
        slds[r * C + c] = csb[(size_t)c * CS_STRIDE + t];
    }
    for (int i = tid; i < K * C; i += 256) sllp[i] = llp[i];
    __syncthreads();

    const int c4 = (tid & 7) << 2;
    const int tb = tid >> 3;
    const int ja = tb + K;
    const int jb = ja + 32;
    const int ta = t0 + tb;
    const int tbig = t0 + 32 + tb;

    const f32x4 ea = *(const f32x4*)&slds[(ja + 1) * C + c4];
    const f32x4 eb = *(const f32x4*)&slds[(jb + 1) * C + c4];

    float* ob = out + ((size_t)(b * K) * T + t0) * C + c4;

    for (int k = 0; k < K; ++k) {
        const f32x4 lv = *(const f32x4*)&sllp[k * C + c4];
        const f32x4 sa = *(const f32x4*)&slds[(ja - k) * C + c4];
        const f32x4 sb = *(const f32x4*)&slds[(jb - k) * C + c4];
        f32x4 ra = ea - sa + lv;
        f32x4 rb = eb - sb + lv;
        if (ta < k) ra = BIG_NEG + lv;
        if (tbig < k) rb = BIG_NEG + lv;
        float* op = ob + (size_t)k * T * C;
        *(f32x4*)(op + tb * C) = ra;
        *(f32x4*)(op + (32 + tb) * C) = rb;
    }
}

// ---------------------------------------------------------------------------
extern "C" void kernel_launch(void* const* d_in, const int* in_sizes, int n_in,
                              void* d_out, int out_size, void* d_ws, size_t ws_size,
                              hipStream_t stream) {
    const float* feat   = (const float*)d_in[0];
    const float* P      = (const float*)d_in[1];
    const float* TL     = (const float*)d_in[2];
    const float* TR     = (const float*)d_in[3];
    const float* MEANS  = (const float*)d_in[4];
    const float* STDV   = (const float*)d_in[5];
    const float* PLR    = (const float*)d_in[6];
    const float* LOGITS = (const float*)d_in[7];

    const int K = (out_size - (C * C + C)) / (B * T * C);

    float* ws  = (float*)d_ws;
    float* llp = ws + 128;
    float* emT = ws + 4096;
    float* cs  = emT + (size_t)B * C * T;

    float* out       = (float*)d_out;
    float* out_trans = out + (size_t)B * K * T * C;
    float* out_init  = out_trans + C * C;

    prep_kernel<<<1, 1024, 0, stream>>>(P, TL, TR, STDV, MEANS, PLR, LOGITS,
                                        ws, out_trans, out_init, K);
    emission_kernel<<<B * T / 32, 256, 0, stream>>>(feat, ws, emT);
    scan_kernel<<<B * C, 256, 0, stream>>>(emT, cs);

    const int nblk = B * (T / 64);     // 512 blocks: (b, 32 chunks)
    if (K == 20) {
        span_kernel_t<20><<<nblk, 256, 0, stream>>>(cs, llp, out);
    } else if (K == 16) {
        span_kernel_t<16><<<nblk, 256, 0, stream>>>(cs, llp, out);
    } else if (K == 24) {
        span_kernel_t<24><<<nblk, 256, 0, stream>>>(cs, llp, out);
    } else {
        const size_t smem = (size_t)((64 + K + 1) + K) * C * sizeof(float);
        span_kernel_rt<<<nblk, 256, smem, stream>>>(cs, llp, out, K);
    }
}